// Round 3
// baseline (615.514 us; speedup 1.0000x reference)
//
#include <hip/hip_runtime.h>
#include <hip/hip_bf16.h>
#include <math.h>

#define D_MODEL   512
#define N_LAYERS  3
#define D_INNER   1024
#define DT_RANK   32
#define D_STATE   16
#define D_CONV    4
#define RMS_EPS   1e-5f
#define B_SZ      2
#define L_SEQ     1024
#define NTOK      (B_SZ * L_SEQ)   // 2048

typedef __bf16 bf16_t;
typedef bf16_t bf16x8 __attribute__((ext_vector_type(8)));
typedef float  f32x4  __attribute__((ext_vector_type(4)));

// ---------------------------------------------------------------------------
// One-shot: convert all 4 weight tensors f32->bf16 (8 elems/thread) and copy
// the residual x -> out (4 f32/thread). Segmented flat index.
// ---------------------------------------------------------------------------
#define CVT_N1 (N_LAYERS * 2 * D_INNER * D_MODEL)   // 3145728
#define CVT_N2 (N_LAYERS * 64 * D_INNER)            // 196608
#define CVT_N3 (N_LAYERS * D_INNER * DT_RANK)       // 98304
#define CVT_N4 (N_LAYERS * D_MODEL * D_INNER)       // 1572864
#define CVT_S1 (CVT_N1 / 8)
#define CVT_S2 (CVT_S1 + CVT_N2 / 8)
#define CVT_S3 (CVT_S2 + CVT_N3 / 8)
#define CVT_S4 (CVT_S3 + CVT_N4 / 8)
#define CVT_S5 (CVT_S4 + NTOK * D_MODEL / 4)
#define CVT_BLOCKS ((CVT_S5 + 255) / 256)

__device__ __forceinline__ void cvt8(const float* s, bf16_t* d, int idx) {
    int i = idx * 8;
    f32x4 v0 = *(const f32x4*)&s[i];
    f32x4 v1 = *(const f32x4*)&s[i + 4];
    bf16x8 o;
#pragma unroll
    for (int j = 0; j < 4; j++) { o[j] = (bf16_t)v0[j]; o[j + 4] = (bf16_t)v1[j]; }
    *(bf16x8*)&d[i] = o;
}

__global__ __launch_bounds__(256) void cvt_all(const float* __restrict__ ipw,
                                               const float* __restrict__ xpw,
                                               const float* __restrict__ dtw,
                                               const float* __restrict__ opw,
                                               const float* __restrict__ x,
                                               bf16_t* __restrict__ wip,
                                               bf16_t* __restrict__ wxp,
                                               bf16_t* __restrict__ wdt,
                                               bf16_t* __restrict__ wop,
                                               float* __restrict__ out) {
    int t = blockIdx.x * 256 + threadIdx.x;
    if (t < CVT_S1)      cvt8(ipw, wip, t);
    else if (t < CVT_S2) cvt8(xpw, wxp, t - CVT_S1);
    else if (t < CVT_S3) cvt8(dtw, wdt, t - CVT_S2);
    else if (t < CVT_S4) cvt8(opw, wop, t - CVT_S3);
    else if (t < CVT_S5) {
        int i = (t - CVT_S4) * 4;
        *(f32x4*)&out[i] = *(const f32x4*)&x[i];
    }
}

// ---------------------------------------------------------------------------
// Per-token RMS scale only (norm applied inside in_proj staging).
// One wave per token; 4 tokens/block.
// ---------------------------------------------------------------------------
__global__ __launch_bounds__(256) void rms_scale(const float* __restrict__ x,
                                                 float* __restrict__ scales) {
    int wid  = threadIdx.x >> 6;
    int lane = threadIdx.x & 63;
    int token = blockIdx.x * 4 + wid;
    const float* xr = x + (size_t)token * D_MODEL;
    f32x4 v0 = *(const f32x4*)&xr[lane * 8];
    f32x4 v1 = *(const f32x4*)&xr[lane * 8 + 4];
    float ss = 0.f;
#pragma unroll
    for (int i = 0; i < 4; i++) ss += v0[i] * v0[i] + v1[i] * v1[i];
#pragma unroll
    for (int m = 32; m >= 1; m >>= 1) ss += __shfl_xor(ss, m, 64);
    if (lane == 0) scales[token] = rsqrtf(ss * (1.0f / D_MODEL) + RMS_EPS);
}

// ---------------------------------------------------------------------------
// in_proj: xz[2048][2048] = (x * scale * nw) @ wip^T, 128x128 tile, BK=32,
// 4 waves each 64x64 (4x4 of 16x16x32). RMSNorm fused into A-staging.
// ---------------------------------------------------------------------------
__global__ __launch_bounds__(256) void inproj_gemm(const float* __restrict__ x,
                                                   const float* __restrict__ scales,
                                                   const float* __restrict__ nw,
                                                   const bf16_t* __restrict__ W,
                                                   bf16_t* __restrict__ xz) {
    __shared__ bf16_t As[128][40];
    __shared__ bf16_t Bs[128][40];
    int tid = threadIdx.x;
    int m0 = blockIdx.y * 128, n0 = blockIdx.x * 128;
    int wid = tid >> 6, lane = tid & 63;
    int wm = (wid >> 1) * 64, wn = (wid & 1) * 64;
    int lr = lane & 15, kg = lane >> 4;

    f32x4 acc[4][4] = {};

    int srow = tid >> 1, scol = (tid & 1) * 16;
    float rs = scales[m0 + srow];
    const float*  xp = x + (size_t)(m0 + srow) * D_MODEL + scol;
    const bf16_t* wp = W + (size_t)(n0 + srow) * D_MODEL + scol;

    for (int k0 = 0; k0 < D_MODEL; k0 += 32) {
        f32x4 v0 = *(const f32x4*)(xp + k0);
        f32x4 v1 = *(const f32x4*)(xp + k0 + 4);
        f32x4 v2 = *(const f32x4*)(xp + k0 + 8);
        f32x4 v3 = *(const f32x4*)(xp + k0 + 12);
        f32x4 g0 = *(const f32x4*)(nw + k0 + scol);
        f32x4 g1 = *(const f32x4*)(nw + k0 + scol + 4);
        f32x4 g2 = *(const f32x4*)(nw + k0 + scol + 8);
        f32x4 g3 = *(const f32x4*)(nw + k0 + scol + 12);
        bf16x8 a0, a1;
#pragma unroll
        for (int j = 0; j < 4; j++) {
            a0[j]     = (bf16_t)(v0[j] * rs * g0[j]);
            a0[j + 4] = (bf16_t)(v1[j] * rs * g1[j]);
            a1[j]     = (bf16_t)(v2[j] * rs * g2[j]);
            a1[j + 4] = (bf16_t)(v3[j] * rs * g3[j]);
        }
        *(bf16x8*)&As[srow][scol]     = a0;
        *(bf16x8*)&As[srow][scol + 8] = a1;
        *(bf16x8*)&Bs[srow][scol]     = *(const bf16x8*)(wp + k0);
        *(bf16x8*)&Bs[srow][scol + 8] = *(const bf16x8*)(wp + k0 + 8);
        __syncthreads();
        bf16x8 af[4], bfr[4];
#pragma unroll
        for (int f = 0; f < 4; f++) {
            af[f]  = *(const bf16x8*)&As[wm + f * 16 + lr][kg * 8];
            bfr[f] = *(const bf16x8*)&Bs[wn + f * 16 + lr][kg * 8];
        }
#pragma unroll
        for (int fm = 0; fm < 4; fm++)
#pragma unroll
            for (int fn = 0; fn < 4; fn++)
                acc[fm][fn] = __builtin_amdgcn_mfma_f32_16x16x32_bf16(af[fm], bfr[fn], acc[fm][fn], 0, 0, 0);
        __syncthreads();
    }

    int colb = lane & 15, rowb = (lane >> 4) * 4;
#pragma unroll
    for (int fm = 0; fm < 4; fm++)
#pragma unroll
        for (int fn = 0; fn < 4; fn++)
#pragma unroll
            for (int r = 0; r < 4; r++) {
                int row = m0 + wm + fm * 16 + rowb + r;
                int col = n0 + wn + fn * 16 + colb;
                xz[(size_t)row * (2 * D_INNER) + col] = (bf16_t)acc[fm][fn][r];
            }
}

// ---------------------------------------------------------------------------
// Depthwise causal conv (k=4) + bias + silu  -> bf16 xc.
// ---------------------------------------------------------------------------
__global__ __launch_bounds__(256) void conv_silu_kernel(const bf16_t* __restrict__ xz,
                                                        const float* __restrict__ cw,
                                                        const float* __restrict__ cb,
                                                        bf16_t* __restrict__ xc) {
    int idx = blockIdx.x * 256 + threadIdx.x;
    int e = idx & (D_INNER - 1);
    int t = idx >> 10;
    int l = t & (L_SEQ - 1);
    const bf16_t* xp = xz + (size_t)t * (2 * D_INNER) + e;
    float w0 = cw[e * 4], w1 = cw[e * 4 + 1], w2 = cw[e * 4 + 2], w3 = cw[e * 4 + 3];
    float acc = cb[e];
    if (l >= 3) acc += w0 * (float)xp[-3 * 2 * D_INNER];
    if (l >= 2) acc += w1 * (float)xp[-2 * 2 * D_INNER];
    if (l >= 1) acc += w2 * (float)xp[-1 * 2 * D_INNER];
    acc += w3 * (float)xp[0];
    xc[idx] = (bf16_t)(acc / (1.f + __expf(-acc)));
}

// ---------------------------------------------------------------------------
// x_proj + dt_proj + softplus fused. Grid: 32 blocks (64 tokens each).
// Phase 1: dbc(64x64) = xc @ wxp^T (K=1024). cols>=32 -> bc[t][32] f32,
//          cols<32 -> din LDS (bf16).
// Phase 2: delta(64x1024) = softplus(din @ wdt^T + dtb) -> f32.
// ---------------------------------------------------------------------------
__global__ __launch_bounds__(256) void xproj_dtproj(const bf16_t* __restrict__ xc,
                                                    const bf16_t* __restrict__ Wx,
                                                    const bf16_t* __restrict__ Wd,
                                                    const float* __restrict__ dtb,
                                                    float* __restrict__ bc,
                                                    float* __restrict__ delta) {
    __shared__ bf16_t As[64][40];
    __shared__ bf16_t Bs[64][40];
    __shared__ bf16_t din_s[64][40];
    int tid = threadIdx.x;
    int m0 = blockIdx.x * 64;
    int wid = tid >> 6, lane = tid & 63;
    int wm = (wid >> 1) * 32, wn = (wid & 1) * 32;
    int lr = lane & 15, kg = lane >> 4;
    int colb = lane & 15, rowb = (lane >> 4) * 4;

    f32x4 acc[2][2] = {};
    int srow = tid >> 2, scol = (tid & 3) * 8;
    const bf16_t* Ap = xc + (size_t)(m0 + srow) * D_INNER + scol;
    const bf16_t* Wp = Wx + (size_t)srow * D_INNER + scol;

    for (int k0 = 0; k0 < D_INNER; k0 += 32) {
        *(bf16x8*)&As[srow][scol] = *(const bf16x8*)(Ap + k0);
        *(bf16x8*)&Bs[srow][scol] = *(const bf16x8*)(Wp + k0);
        __syncthreads();
        bf16x8 a0 = *(const bf16x8*)&As[wm + lr][kg * 8];
        bf16x8 a1 = *(const bf16x8*)&As[wm + 16 + lr][kg * 8];
        bf16x8 b0 = *(const bf16x8*)&Bs[wn + lr][kg * 8];
        bf16x8 b1 = *(const bf16x8*)&Bs[wn + 16 + lr][kg * 8];
        acc[0][0] = __builtin_amdgcn_mfma_f32_16x16x32_bf16(a0, b0, acc[0][0], 0, 0, 0);
        acc[0][1] = __builtin_amdgcn_mfma_f32_16x16x32_bf16(a0, b1, acc[0][1], 0, 0, 0);
        acc[1][0] = __builtin_amdgcn_mfma_f32_16x16x32_bf16(a1, b0, acc[1][0], 0, 0, 0);
        acc[1][1] = __builtin_amdgcn_mfma_f32_16x16x32_bf16(a1, b1, acc[1][1], 0, 0, 0);
        __syncthreads();
    }

#pragma unroll
    for (int fm = 0; fm < 2; fm++)
#pragma unroll
        for (int fn = 0; fn < 2; fn++)
#pragma unroll
            for (int r = 0; r < 4; r++) {
                int row = wm + fm * 16 + rowb + r;
                int col = wn + fn * 16 + colb;
                float v = acc[fm][fn][r];
                if (col >= DT_RANK) bc[(size_t)(m0 + row) * 32 + (col - DT_RANK)] = v;
                else                din_s[row][col] = (bf16_t)v;
            }
    __syncthreads();

    // Phase 2
    bf16x8 a0 = *(const bf16x8*)&din_s[wm + lr][kg * 8];
    bf16x8 a1 = *(const bf16x8*)&din_s[wm + 16 + lr][kg * 8];
    for (int nt = 0; nt < D_INNER / 64; ++nt) {
        __syncthreads();   // previous-iter Bs reads done
        *(bf16x8*)&Bs[srow][scol] = *(const bf16x8*)(Wd + (size_t)(nt * 64 + srow) * DT_RANK + scol);
        __syncthreads();
        bf16x8 b0 = *(const bf16x8*)&Bs[wn + lr][kg * 8];
        bf16x8 b1 = *(const bf16x8*)&Bs[wn + 16 + lr][kg * 8];
        f32x4 c[2][2] = {};
        c[0][0] = __builtin_amdgcn_mfma_f32_16x16x32_bf16(a0, b0, c[0][0], 0, 0, 0);
        c[0][1] = __builtin_amdgcn_mfma_f32_16x16x32_bf16(a0, b1, c[0][1], 0, 0, 0);
        c[1][0] = __builtin_amdgcn_mfma_f32_16x16x32_bf16(a1, b0, c[1][0], 0, 0, 0);
        c[1][1] = __builtin_amdgcn_mfma_f32_16x16x32_bf16(a1, b1, c[1][1], 0, 0, 0);
#pragma unroll
        for (int fm = 0; fm < 2; fm++)
#pragma unroll
            for (int fn = 0; fn < 2; fn++)
#pragma unroll
                for (int r = 0; r < 4; r++) {
                    int row = m0 + wm + fm * 16 + rowb + r;
                    int e   = nt * 64 + wn + fn * 16 + colb;
                    float t = c[fm][fn][r] + dtb[e];
                    delta[(size_t)row * D_INNER + e] = (t > 15.f) ? t : log1pf(__expf(t));
                }
    }
}

// ---------------------------------------------------------------------------
// Chunked selective scan pass 1 (chunk-local, h from 0; stores P[16], hf[16]).
// ---------------------------------------------------------------------------
__global__ __launch_bounds__(256) void scan_part1(const float* __restrict__ delta,
                                                  const bf16_t* __restrict__ xc,
                                                  const float* __restrict__ bc,
                                                  const float* __restrict__ A_log,
                                                  float* __restrict__ cs, int nc) {
    int T = L_SEQ / nc;
    int e = blockIdx.x * 256 + threadIdx.x;
    int c = blockIdx.y;
    int b = blockIdx.z;
    size_t t0 = (size_t)b * L_SEQ + (size_t)c * T;

    __shared__ float Bs[32][16];
    for (int i = threadIdx.x; i < T * 16; i += 256)
        Bs[i >> 4][i & 15] = bc[(t0 + (i >> 4)) * 32 + (i & 15)];
    __syncthreads();

    float Aa[16], h[16], P[16];
    const float* Ae = A_log + (size_t)e * D_STATE;
#pragma unroll
    for (int n = 0; n < 16; n++) { Aa[n] = -__expf(Ae[n]); h[n] = 0.f; P[n] = 1.f; }

    const float*  dp = delta + t0 * D_INNER + e;
    const bf16_t* xp = xc    + t0 * D_INNER + e;

    float dv = dp[0], xv = (float)xp[0];
    for (int l = 0; l < T; ++l) {
        float dv2 = 0.f, xv2 = 0.f;
        if (l + 1 < T) {
            dv2 = dp[(l + 1) * D_INNER];
            xv2 = (float)xp[(l + 1) * D_INNER];
        }
        float dx = dv * xv;
#pragma unroll
        for (int n = 0; n < 16; n++) {
            float dA = __expf(dv * Aa[n]);
            h[n] = dA * h[n] + dx * Bs[l][n];
            P[n] *= dA;
        }
        dv = dv2; xv = xv2;
    }

    float* o = cs + (size_t)(b * nc + c) * 32 * D_INNER + e;
#pragma unroll
    for (int n = 0; n < 16; n++) {
        o[n * D_INNER]        = P[n];
        o[(16 + n) * D_INNER] = h[n];
    }
}

// ---------------------------------------------------------------------------
// Pass 2: sequential combine over chunks per (b, e, n); h_init overwrites P.
// ---------------------------------------------------------------------------
__global__ __launch_bounds__(256) void scan_combine(float* __restrict__ cs, int nc) {
    int e = blockIdx.x * 256 + threadIdx.x;
    int n = blockIdx.y;
    int b = blockIdx.z;
    size_t stride = (size_t)32 * D_INNER;
    float* p = cs + ((size_t)b * nc * 32 + n) * D_INNER + e;

    float h = 0.f;
    float P = p[0], hf = p[16 * D_INNER];
    for (int c = 0; c < nc; ++c) {
        float P2 = 0.f, hf2 = 0.f;
        if (c + 1 < nc) {
            P2  = p[(c + 1) * stride];
            hf2 = p[(c + 1) * stride + 16 * D_INNER];
        }
        p[c * stride] = h;
        h = P * h + hf;
        P = P2; hf = hf2;
    }
}

// ---------------------------------------------------------------------------
// Pass 3: re-scan seeded with h_init; fuse y = (sum h*C + D*x)*silu(z) -> bf16.
// ---------------------------------------------------------------------------
__global__ __launch_bounds__(256) void scan_part3(const float* __restrict__ delta,
                                                  const bf16_t* __restrict__ xc,
                                                  const float* __restrict__ bc,
                                                  const bf16_t* __restrict__ xz,
                                                  const float* __restrict__ A_log,
                                                  const float* __restrict__ Dskip,
                                                  const float* __restrict__ cs,
                                                  bf16_t* __restrict__ yz, int nc) {
    int T = L_SEQ / nc;
    int e = blockIdx.x * 256 + threadIdx.x;
    int c = blockIdx.y;
    int b = blockIdx.z;
    size_t t0 = (size_t)b * L_SEQ + (size_t)c * T;

    __shared__ float BCs[32][32];
    for (int i = threadIdx.x; i < T * 32; i += 256)
        BCs[i >> 5][i & 31] = bc[(t0 + (i >> 5)) * 32 + (i & 31)];
    __syncthreads();

    float Aa[16], h[16];
    const float* Ae = A_log + (size_t)e * D_STATE;
    const float* hi = cs + (size_t)(b * nc + c) * 32 * D_INNER + e;
#pragma unroll
    for (int n = 0; n < 16; n++) {
        Aa[n] = -__expf(Ae[n]);
        h[n]  = hi[n * D_INNER];
    }
    float Dv = Dskip[e];

    const float*  dp = delta + t0 * D_INNER + e;
    const bf16_t* xp = xc    + t0 * D_INNER + e;
    const bf16_t* zp = xz    + t0 * 2 * D_INNER + D_INNER + e;
    bf16_t*       yp = yz    + t0 * D_INNER + e;

    float dv = dp[0], xv = (float)xp[0], zv = (float)zp[0];
    for (int l = 0; l < T; ++l) {
        float dv2 = 0.f, xv2 = 0.f, zv2 = 0.f;
        if (l + 1 < T) {
            dv2 = dp[(l + 1) * D_INNER];
            xv2 = (float)xp[(l + 1) * D_INNER];
            zv2 = (float)zp[(l + 1) * 2 * D_INNER];
        }
        float dx = dv * xv;
        float y  = Dv * xv;
#pragma unroll
        for (int n = 0; n < 16; n++) {
            float dA = __expf(dv * Aa[n]);
            h[n] = dA * h[n] + dx * BCs[l][n];
            y   += h[n] * BCs[l][16 + n];
        }
        yp[l * D_INNER] = (bf16_t)(y * (zv / (1.f + __expf(-zv))));
        dv = dv2; xv = xv2; zv = zv2;
    }
}

// ---------------------------------------------------------------------------
// out_proj: out[2048][512] += yz @ wop^T (K=1024), 64x64 tile.
// ---------------------------------------------------------------------------
__global__ __launch_bounds__(256) void outproj_gemm(const bf16_t* __restrict__ A,
                                                    const bf16_t* __restrict__ W,
                                                    float* __restrict__ out) {
    __shared__ bf16_t As[64][40];
    __shared__ bf16_t Bs[64][40];
    int tid = threadIdx.x;
    int m0 = blockIdx.y * 64, n0 = blockIdx.x * 64;
    int wid = tid >> 6, lane = tid & 63;
    int wm = (wid >> 1) * 32, wn = (wid & 1) * 32;
    int lr = lane & 15, kg = lane >> 4;

    f32x4 acc[2][2] = {};
    int srow = tid >> 2, scol = (tid & 3) * 8;
    const bf16_t* Ap = A + (size_t)(m0 + srow) * D_INNER + scol;
    const bf16_t* Wp = W + (size_t)(n0 + srow) * D_INNER + scol;

    for (int k0 = 0; k0 < D_INNER; k0 += 32) {
        *(bf16x8*)&As[srow][scol] = *(const bf16x8*)(Ap + k0);
        *(bf16x8*)&Bs[srow][scol] = *(const bf16x8*)(Wp + k0);
        __syncthreads();
        bf16x8 a0 = *(const bf16x8*)&As[wm + lr][kg * 8];
        bf16x8 a1 = *(const bf16x8*)&As[wm + 16 + lr][kg * 8];
        bf16x8 b0 = *(const bf16x8*)&Bs[wn + lr][kg * 8];
        bf16x8 b1 = *(const bf16x8*)&Bs[wn + 16 + lr][kg * 8];
        acc[0][0] = __builtin_amdgcn_mfma_f32_16x16x32_bf16(a0, b0, acc[0][0], 0, 0, 0);
        acc[0][1] = __builtin_amdgcn_mfma_f32_16x16x32_bf16(a0, b1, acc[0][1], 0, 0, 0);
        acc[1][0] = __builtin_amdgcn_mfma_f32_16x16x32_bf16(a1, b0, acc[1][0], 0, 0, 0);
        acc[1][1] = __builtin_amdgcn_mfma_f32_16x16x32_bf16(a1, b1, acc[1][1], 0, 0, 0);
        __syncthreads();
    }

    int colb = lane & 15, rowb = (lane >> 4) * 4;
#pragma unroll
    for (int fm = 0; fm < 2; fm++)
#pragma unroll
        for (int fn = 0; fn < 2; fn++)
#pragma unroll
            for (int r = 0; r < 4; r++) {
                int row = m0 + wm + fm * 16 + rowb + r;
                int col = n0 + wn + fn * 16 + colb;
                out[(size_t)row * D_MODEL + col] += acc[fm][fn][r];
            }
}

// ---------------------------------------------------------------------------
extern "C" void kernel_launch(void* const* d_in, const int* in_sizes, int n_in,
                              void* d_out, int out_size, void* d_ws, size_t ws_size,
                              hipStream_t stream) {
    const float* x_in  = (const float*)d_in[0];
    const float* ipw   = (const float*)d_in[1];
    const float* cw    = (const float*)d_in[2];
    const float* cb    = (const float*)d_in[3];
    const float* xpw   = (const float*)d_in[4];
    const float* dtw   = (const float*)d_in[5];
    const float* dtb   = (const float*)d_in[6];
    const float* A_log = (const float*)d_in[7];
    const float* Dsk   = (const float*)d_in[8];
    const float* opw   = (const float*)d_in[9];
    const float* nw    = (const float*)d_in[10];
    float* out = (float*)d_out;

    char* ws = (char*)d_ws;
    size_t off = 0;
    auto alloc = [&](size_t bytes) -> void* {
        void* p = ws + off;
        off += (bytes + 255) & ~(size_t)255;
        return p;
    };
    bf16_t* wip    = (bf16_t*)alloc((size_t)CVT_N1 * 2);
    bf16_t* wxp    = (bf16_t*)alloc((size_t)CVT_N2 * 2);
    bf16_t* wdt    = (bf16_t*)alloc((size_t)CVT_N3 * 2);
    bf16_t* wop    = (bf16_t*)alloc((size_t)CVT_N4 * 2);
    bf16_t* xz_bf  = (bf16_t*)alloc((size_t)NTOK * 2 * D_INNER * 2);
    bf16_t* xc_bf  = (bf16_t*)alloc((size_t)NTOK * D_INNER * 2);
    float*  bcbuf  = (float*)alloc((size_t)NTOK * 32 * 4);
    float*  deltaf = (float*)alloc((size_t)NTOK * D_INNER * 4);
    bf16_t* yz_bf  = (bf16_t*)alloc((size_t)NTOK * D_INNER * 2);
    float*  scales = (float*)alloc((size_t)NTOK * 4);

    int nc = 64;
    if (off + (size_t)B_SZ * nc * 32 * D_INNER * 4 > ws_size) nc = 32;
    float* cstate = (float*)alloc((size_t)B_SZ * nc * 32 * D_INNER * 4);

    // weights -> bf16, residual x -> out, one dispatch
    cvt_all<<<CVT_BLOCKS, 256, 0, stream>>>(ipw, xpw, dtw, opw, x_in,
                                            wip, wxp, wdt, wop, out);

    for (int l = 0; l < N_LAYERS; ++l) {
        const float* Al = A_log + (size_t)l * D_INNER * D_STATE;
        rms_scale<<<NTOK / 4, 256, 0, stream>>>(out, scales);
        inproj_gemm<<<dim3(2 * D_INNER / 128, NTOK / 128), 256, 0, stream>>>(
            out, scales, nw + (size_t)l * D_MODEL,
            wip + (size_t)l * 2 * D_INNER * D_MODEL, xz_bf);
        conv_silu_kernel<<<NTOK * D_INNER / 256, 256, 0, stream>>>(
            xz_bf, cw + (size_t)l * D_INNER * D_CONV, cb + (size_t)l * D_INNER, xc_bf);
        xproj_dtproj<<<NTOK / 64, 256, 0, stream>>>(
            xc_bf, wxp + (size_t)l * 64 * D_INNER, wdt + (size_t)l * D_INNER * DT_RANK,
            dtb + (size_t)l * D_INNER, bcbuf, deltaf);
        scan_part1<<<dim3(D_INNER / 256, nc, B_SZ), 256, 0, stream>>>(
            deltaf, xc_bf, bcbuf, Al, cstate, nc);
        scan_combine<<<dim3(D_INNER / 256, D_STATE, B_SZ), 256, 0, stream>>>(
            cstate, nc);
        scan_part3<<<dim3(D_INNER / 256, nc, B_SZ), 256, 0, stream>>>(
            deltaf, xc_bf, bcbuf, xz_bf, Al, Dsk + (size_t)l * D_INNER, cstate,
            yz_bf, nc);
        outproj_gemm<<<dim3(D_MODEL / 64, NTOK / 64), 256, 0, stream>>>(
            yz_bf, wop + (size_t)l * D_MODEL * D_INNER, out);
    }
}

// Round 4
// 293.052 us; speedup vs baseline: 2.1004x; 2.1004x over previous
//
#include <hip/hip_runtime.h>
#include <hip/hip_bf16.h>
#include <math.h>

#define D_MODEL   512
#define N_LAYERS  3
#define D_INNER   1024
#define DT_RANK   32
#define D_STATE   16
#define D_CONV    4
#define RMS_EPS   1e-5f
#define B_SZ      2
#define L_SEQ     1024
#define NTOK      (B_SZ * L_SEQ)   // 2048

typedef __bf16 bf16_t;
typedef bf16_t bf16x8 __attribute__((ext_vector_type(8)));
typedef float  f32x4  __attribute__((ext_vector_type(4)));

// ---------------------------------------------------------------------------
// One-shot: convert all 4 weight tensors f32->bf16 (8 elems/thread) and copy
// the residual x -> out (4 f32/thread). Segmented flat index.
// ---------------------------------------------------------------------------
#define CVT_N1 (N_LAYERS * 2 * D_INNER * D_MODEL)
#define CVT_N2 (N_LAYERS * 64 * D_INNER)
#define CVT_N3 (N_LAYERS * D_INNER * DT_RANK)
#define CVT_N4 (N_LAYERS * D_MODEL * D_INNER)
#define CVT_S1 (CVT_N1 / 8)
#define CVT_S2 (CVT_S1 + CVT_N2 / 8)
#define CVT_S3 (CVT_S2 + CVT_N3 / 8)
#define CVT_S4 (CVT_S3 + CVT_N4 / 8)
#define CVT_S5 (CVT_S4 + NTOK * D_MODEL / 4)
#define CVT_BLOCKS ((CVT_S5 + 255) / 256)

__device__ __forceinline__ void cvt8(const float* s, bf16_t* d, int idx) {
    int i = idx * 8;
    f32x4 v0 = *(const f32x4*)&s[i];
    f32x4 v1 = *(const f32x4*)&s[i + 4];
    bf16x8 o;
#pragma unroll
    for (int j = 0; j < 4; j++) { o[j] = (bf16_t)v0[j]; o[j + 4] = (bf16_t)v1[j]; }
    *(bf16x8*)&d[i] = o;
}

__global__ __launch_bounds__(256) void cvt_all(const float* __restrict__ ipw,
                                               const float* __restrict__ xpw,
                                               const float* __restrict__ dtw,
                                               const float* __restrict__ opw,
                                               const float* __restrict__ x,
                                               bf16_t* __restrict__ wip,
                                               bf16_t* __restrict__ wxp,
                                               bf16_t* __restrict__ wdt,
                                               bf16_t* __restrict__ wop,
                                               float* __restrict__ out) {
    int t = blockIdx.x * 256 + threadIdx.x;
    if (t < CVT_S1)      cvt8(ipw, wip, t);
    else if (t < CVT_S2) cvt8(xpw, wxp, t - CVT_S1);
    else if (t < CVT_S3) cvt8(dtw, wdt, t - CVT_S2);
    else if (t < CVT_S4) cvt8(opw, wop, t - CVT_S3);
    else if (t < CVT_S5) {
        int i = (t - CVT_S4) * 4;
        *(f32x4*)&out[i] = *(const f32x4*)&x[i];
    }
}

// ---------------------------------------------------------------------------
// Per-token RMS scale + zero the dbc accumulator (2048*64 = grid*block exact).
// ---------------------------------------------------------------------------
__global__ __launch_bounds__(256) void rms_scale(const float* __restrict__ x,
                                                 float* __restrict__ scales,
                                                 float* __restrict__ dbcf) {
    dbcf[blockIdx.x * 256 + threadIdx.x] = 0.f;
    int wid  = threadIdx.x >> 6;
    int lane = threadIdx.x & 63;
    int token = blockIdx.x * 4 + wid;
    const float* xr = x + (size_t)token * D_MODEL;
    f32x4 v0 = *(const f32x4*)&xr[lane * 8];
    f32x4 v1 = *(const f32x4*)&xr[lane * 8 + 4];
    float ss = 0.f;
#pragma unroll
    for (int i = 0; i < 4; i++) ss += v0[i] * v0[i] + v1[i] * v1[i];
#pragma unroll
    for (int m = 32; m >= 1; m >>= 1) ss += __shfl_xor(ss, m, 64);
    if (lane == 0) scales[token] = rsqrtf(ss * (1.0f / D_MODEL) + RMS_EPS);
}

// ---------------------------------------------------------------------------
// in_proj: xz[2048][2048] = (x * scale * nw) @ wip^T, 128x128 tile, BK=32.
// ---------------------------------------------------------------------------
__global__ __launch_bounds__(256) void inproj_gemm(const float* __restrict__ x,
                                                   const float* __restrict__ scales,
                                                   const float* __restrict__ nw,
                                                   const bf16_t* __restrict__ W,
                                                   bf16_t* __restrict__ xz) {
    __shared__ bf16_t As[128][40];
    __shared__ bf16_t Bs[128][40];
    int tid = threadIdx.x;
    int m0 = blockIdx.y * 128, n0 = blockIdx.x * 128;
    int wid = tid >> 6, lane = tid & 63;
    int wm = (wid >> 1) * 64, wn = (wid & 1) * 64;
    int lr = lane & 15, kg = lane >> 4;

    f32x4 acc[4][4] = {};

    int srow = tid >> 1, scol = (tid & 1) * 16;
    float rs = scales[m0 + srow];
    const float*  xp = x + (size_t)(m0 + srow) * D_MODEL + scol;
    const bf16_t* wp = W + (size_t)(n0 + srow) * D_MODEL + scol;

    for (int k0 = 0; k0 < D_MODEL; k0 += 32) {
        f32x4 v0 = *(const f32x4*)(xp + k0);
        f32x4 v1 = *(const f32x4*)(xp + k0 + 4);
        f32x4 v2 = *(const f32x4*)(xp + k0 + 8);
        f32x4 v3 = *(const f32x4*)(xp + k0 + 12);
        f32x4 g0 = *(const f32x4*)(nw + k0 + scol);
        f32x4 g1 = *(const f32x4*)(nw + k0 + scol + 4);
        f32x4 g2 = *(const f32x4*)(nw + k0 + scol + 8);
        f32x4 g3 = *(const f32x4*)(nw + k0 + scol + 12);
        bf16x8 a0, a1;
#pragma unroll
        for (int j = 0; j < 4; j++) {
            a0[j]     = (bf16_t)(v0[j] * rs * g0[j]);
            a0[j + 4] = (bf16_t)(v1[j] * rs * g1[j]);
            a1[j]     = (bf16_t)(v2[j] * rs * g2[j]);
            a1[j + 4] = (bf16_t)(v3[j] * rs * g3[j]);
        }
        *(bf16x8*)&As[srow][scol]     = a0;
        *(bf16x8*)&As[srow][scol + 8] = a1;
        *(bf16x8*)&Bs[srow][scol]     = *(const bf16x8*)(wp + k0);
        *(bf16x8*)&Bs[srow][scol + 8] = *(const bf16x8*)(wp + k0 + 8);
        __syncthreads();
        bf16x8 af[4], bfr[4];
#pragma unroll
        for (int f = 0; f < 4; f++) {
            af[f]  = *(const bf16x8*)&As[wm + f * 16 + lr][kg * 8];
            bfr[f] = *(const bf16x8*)&Bs[wn + f * 16 + lr][kg * 8];
        }
#pragma unroll
        for (int fm = 0; fm < 4; fm++)
#pragma unroll
            for (int fn = 0; fn < 4; fn++)
                acc[fm][fn] = __builtin_amdgcn_mfma_f32_16x16x32_bf16(af[fm], bfr[fn], acc[fm][fn], 0, 0, 0);
        __syncthreads();
    }

    int colb = lane & 15, rowb = (lane >> 4) * 4;
#pragma unroll
    for (int fm = 0; fm < 4; fm++)
#pragma unroll
        for (int fn = 0; fn < 4; fn++)
#pragma unroll
            for (int r = 0; r < 4; r++) {
                int row = m0 + wm + fm * 16 + rowb + r;
                int col = n0 + wn + fn * 16 + colb;
                xz[(size_t)row * (2 * D_INNER) + col] = (bf16_t)acc[fm][fn][r];
            }
}

// ---------------------------------------------------------------------------
// x_proj with fused depthwise conv+silu, split-K.
// Grid (8 kc, 32 mb). Each block: 64-token x 64-out tile over K-chunk of 128.
// A-staging computes xc = silu(conv(xz)+cb) from xz taps, stores xc to global
// (each (token,e) covered exactly once across the grid), then MFMA;
// epilogue atomicAdd into dbcf[2048][64] (zeroed by rms_scale).
// ---------------------------------------------------------------------------
__global__ __launch_bounds__(256) void xproj_conv(const bf16_t* __restrict__ xz,
                                                  const float* __restrict__ cw,
                                                  const float* __restrict__ cb,
                                                  const bf16_t* __restrict__ Wx,
                                                  bf16_t* __restrict__ xc,
                                                  float* __restrict__ dbcf) {
    __shared__ bf16_t As[64][40];
    __shared__ bf16_t Bs[64][40];
    int tid = threadIdx.x;
    int kc = blockIdx.x;           // K-chunk (128 wide)
    int m0 = blockIdx.y * 64;      // token tile
    int wid = tid >> 6, lane = tid & 63;
    int wm = (wid >> 1) * 32, wn = (wid & 1) * 32;
    int lr = lane & 15, kg = lane >> 4;

    f32x4 acc[2][2] = {};
    int srow = tid >> 2, scol = (tid & 3) * 8;
    int token = m0 + srow;
    int l = token & (L_SEQ - 1);
    const bf16_t* base = xz + (size_t)token * (2 * D_INNER) + kc * 128 + scol;
    // clamped tap row pointers (in-bounds; contribution masked below)
    const bf16_t* b1 = base - (l >= 1 ? 1 : 0) * 2 * D_INNER;
    const bf16_t* b2 = base - (l >= 2 ? 2 : 0) * 2 * D_INNER;
    const bf16_t* b3 = base - (l >= 3 ? 3 : 0) * 2 * D_INNER;
    const bf16_t* wrow = Wx + (size_t)srow * D_INNER + kc * 128 + scol;

    for (int k0 = 0; k0 < 128; k0 += 32) {
        int e = kc * 128 + k0 + scol;
        bf16x8 t0v = *(const bf16x8*)(base + k0);
        bf16x8 t1v = *(const bf16x8*)(b1 + k0);
        bf16x8 t2v = *(const bf16x8*)(b2 + k0);
        bf16x8 t3v = *(const bf16x8*)(b3 + k0);
        bf16x8 a;
#pragma unroll
        for (int j = 0; j < 8; j++) {
            f32x4 w = *(const f32x4*)&cw[(e + j) * 4];
            float av = cb[e + j] + w[3] * (float)t0v[j];
            if (l >= 1) av += w[2] * (float)t1v[j];
            if (l >= 2) av += w[1] * (float)t2v[j];
            if (l >= 3) av += w[0] * (float)t3v[j];
            a[j] = (bf16_t)(av / (1.f + __expf(-av)));
        }
        *(bf16x8*)&As[srow][scol] = a;
        *(bf16x8*)&xc[(size_t)token * D_INNER + e] = a;
        *(bf16x8*)&Bs[srow][scol] = *(const bf16x8*)(wrow + k0);
        __syncthreads();
        bf16x8 a0 = *(const bf16x8*)&As[wm + lr][kg * 8];
        bf16x8 a1 = *(const bf16x8*)&As[wm + 16 + lr][kg * 8];
        bf16x8 b0 = *(const bf16x8*)&Bs[wn + lr][kg * 8];
        bf16x8 bb1 = *(const bf16x8*)&Bs[wn + 16 + lr][kg * 8];
        acc[0][0] = __builtin_amdgcn_mfma_f32_16x16x32_bf16(a0, b0, acc[0][0], 0, 0, 0);
        acc[0][1] = __builtin_amdgcn_mfma_f32_16x16x32_bf16(a0, bb1, acc[0][1], 0, 0, 0);
        acc[1][0] = __builtin_amdgcn_mfma_f32_16x16x32_bf16(a1, b0, acc[1][0], 0, 0, 0);
        acc[1][1] = __builtin_amdgcn_mfma_f32_16x16x32_bf16(a1, bb1, acc[1][1], 0, 0, 0);
        __syncthreads();
    }

    int colb = lane & 15, rowb = (lane >> 4) * 4;
#pragma unroll
    for (int fm = 0; fm < 2; fm++)
#pragma unroll
        for (int fn = 0; fn < 2; fn++)
#pragma unroll
            for (int r = 0; r < 4; r++) {
                int row = m0 + wm + fm * 16 + rowb + r;
                int col = wn + fn * 16 + colb;
                atomicAdd(&dbcf[(size_t)row * 64 + col], acc[fm][fn][r]);
            }
}

// ---------------------------------------------------------------------------
// dt_proj: delta[2048][1024] = softplus(dbcf[:, :32] @ Wd^T + dtb).
// Grid (16 n-tiles, 32 m-tiles), 64x64 tile, single K=32 step.
// ---------------------------------------------------------------------------
__global__ __launch_bounds__(256) void dtproj(const float* __restrict__ dbcf,
                                              const bf16_t* __restrict__ Wd,
                                              const float* __restrict__ dtb,
                                              float* __restrict__ delta) {
    __shared__ bf16_t As[64][40];
    __shared__ bf16_t Bs[64][40];
    int tid = threadIdx.x;
    int n0 = blockIdx.x * 64, m0 = blockIdx.y * 64;
    int wid = tid >> 6, lane = tid & 63;
    int wm = (wid >> 1) * 32, wn = (wid & 1) * 32;
    int lr = lane & 15, kg = lane >> 4;

    int srow = tid >> 2, scol = (tid & 3) * 8;
    f32x4 v0 = *(const f32x4*)&dbcf[(size_t)(m0 + srow) * 64 + scol];
    f32x4 v1 = *(const f32x4*)&dbcf[(size_t)(m0 + srow) * 64 + scol + 4];
    bf16x8 a;
#pragma unroll
    for (int j = 0; j < 4; j++) { a[j] = (bf16_t)v0[j]; a[j + 4] = (bf16_t)v1[j]; }
    *(bf16x8*)&As[srow][scol] = a;
    *(bf16x8*)&Bs[srow][scol] = *(const bf16x8*)(Wd + (size_t)(n0 + srow) * DT_RANK + scol);
    __syncthreads();

    bf16x8 a0 = *(const bf16x8*)&As[wm + lr][kg * 8];
    bf16x8 a1 = *(const bf16x8*)&As[wm + 16 + lr][kg * 8];
    bf16x8 b0 = *(const bf16x8*)&Bs[wn + lr][kg * 8];
    bf16x8 b1 = *(const bf16x8*)&Bs[wn + 16 + lr][kg * 8];
    f32x4 acc[2][2] = {};
    acc[0][0] = __builtin_amdgcn_mfma_f32_16x16x32_bf16(a0, b0, acc[0][0], 0, 0, 0);
    acc[0][1] = __builtin_amdgcn_mfma_f32_16x16x32_bf16(a0, b1, acc[0][1], 0, 0, 0);
    acc[1][0] = __builtin_amdgcn_mfma_f32_16x16x32_bf16(a1, b0, acc[1][0], 0, 0, 0);
    acc[1][1] = __builtin_amdgcn_mfma_f32_16x16x32_bf16(a1, b1, acc[1][1], 0, 0, 0);

    int colb = lane & 15, rowb = (lane >> 4) * 4;
#pragma unroll
    for (int fm = 0; fm < 2; fm++)
#pragma unroll
        for (int fn = 0; fn < 2; fn++)
#pragma unroll
            for (int r = 0; r < 4; r++) {
                int row = m0 + wm + fm * 16 + rowb + r;
                int e   = n0 + wn + fn * 16 + colb;
                float t = acc[fm][fn][r] + dtb[e];
                delta[(size_t)row * D_INNER + e] = (t > 15.f) ? t : log1pf(__expf(t));
            }
}

// ---------------------------------------------------------------------------
// Chunked scan pass 1 (chunk-local, h from 0; stores P[16], hf[16]).
// Full-chunk prefetch of dv/xv (static indices).
// ---------------------------------------------------------------------------
template <int T>
__global__ __launch_bounds__(256) void scan_part1(const float* __restrict__ delta,
                                                  const bf16_t* __restrict__ xc,
                                                  const float* __restrict__ dbcf,
                                                  const float* __restrict__ A_log,
                                                  float* __restrict__ cs, int nc) {
    int e = blockIdx.x * 256 + threadIdx.x;
    int c = blockIdx.y;
    int b = blockIdx.z;
    size_t t0 = (size_t)b * L_SEQ + (size_t)c * T;

    __shared__ float Bs[T][16];
    for (int i = threadIdx.x; i < T * 16; i += 256)
        Bs[i >> 4][i & 15] = dbcf[(t0 + (i >> 4)) * 64 + 32 + (i & 15)];
    __syncthreads();

    float Aa[16], h[16], P[16];
    const float* Ae = A_log + (size_t)e * D_STATE;
#pragma unroll
    for (int n = 0; n < 16; n++) { Aa[n] = -__expf(Ae[n]); h[n] = 0.f; P[n] = 1.f; }

    const float*  dp = delta + t0 * D_INNER + e;
    const bf16_t* xp = xc    + t0 * D_INNER + e;
    float dvs[T], xvs[T];
#pragma unroll
    for (int j = 0; j < T; j++) dvs[j] = dp[j * D_INNER];
#pragma unroll
    for (int j = 0; j < T; j++) xvs[j] = (float)xp[j * D_INNER];

#pragma unroll
    for (int l = 0; l < T; ++l) {
        float dx = dvs[l] * xvs[l];
#pragma unroll
        for (int n = 0; n < 16; n++) {
            float dA = __expf(dvs[l] * Aa[n]);
            h[n] = dA * h[n] + dx * Bs[l][n];
            P[n] *= dA;
        }
    }

    float* o = cs + (size_t)(b * nc + c) * 32 * D_INNER + e;
#pragma unroll
    for (int n = 0; n < 16; n++) {
        o[n * D_INNER]        = P[n];
        o[(16 + n) * D_INNER] = h[n];
    }
}

// ---------------------------------------------------------------------------
// Pass 2: sequential combine over chunks; batch-8 prefetch to hide latency.
// ---------------------------------------------------------------------------
__global__ __launch_bounds__(256) void scan_combine(float* __restrict__ cs, int nc) {
    int e = blockIdx.x * 256 + threadIdx.x;
    int n = blockIdx.y;
    int b = blockIdx.z;
    size_t stride = (size_t)32 * D_INNER;
    float* p = cs + ((size_t)b * nc * 32 + n) * D_INNER + e;

    float h = 0.f;
    for (int base = 0; base < nc; base += 8) {
        float Pv[8], hv[8];
#pragma unroll
        for (int j = 0; j < 8; j++) {
            Pv[j] = p[(base + j) * stride];
            hv[j] = p[(base + j) * stride + 16 * D_INNER];
        }
#pragma unroll
        for (int j = 0; j < 8; j++) {
            p[(base + j) * stride] = h;     // h_init for chunk base+j
            h = Pv[j] * h + hv[j];
        }
    }
}

// ---------------------------------------------------------------------------
// Pass 3: re-scan seeded with h_init; fuse y = (sum h*C + D*x)*silu(z) -> bf16.
// ---------------------------------------------------------------------------
template <int T>
__global__ __launch_bounds__(256) void scan_part3(const float* __restrict__ delta,
                                                  const bf16_t* __restrict__ xc,
                                                  const float* __restrict__ dbcf,
                                                  const bf16_t* __restrict__ xz,
                                                  const float* __restrict__ A_log,
                                                  const float* __restrict__ Dskip,
                                                  const float* __restrict__ cs,
                                                  bf16_t* __restrict__ yz, int nc) {
    int e = blockIdx.x * 256 + threadIdx.x;
    int c = blockIdx.y;
    int b = blockIdx.z;
    size_t t0 = (size_t)b * L_SEQ + (size_t)c * T;

    __shared__ float BCs[T][32];
    for (int i = threadIdx.x; i < T * 32; i += 256)
        BCs[i >> 5][i & 31] = dbcf[(t0 + (i >> 5)) * 64 + 32 + (i & 31)];
    __syncthreads();

    float Aa[16], h[16];
    const float* Ae = A_log + (size_t)e * D_STATE;
    const float* hi = cs + (size_t)(b * nc + c) * 32 * D_INNER + e;
#pragma unroll
    for (int n = 0; n < 16; n++) {
        Aa[n] = -__expf(Ae[n]);
        h[n]  = hi[n * D_INNER];
    }
    float Dv = Dskip[e];

    const float*  dp = delta + t0 * D_INNER + e;
    const bf16_t* xp = xc    + t0 * D_INNER + e;
    const bf16_t* zp = xz    + t0 * 2 * D_INNER + D_INNER + e;
    bf16_t*       yp = yz    + t0 * D_INNER + e;

    float dvs[T], xvs[T], zvs[T];
#pragma unroll
    for (int j = 0; j < T; j++) dvs[j] = dp[j * D_INNER];
#pragma unroll
    for (int j = 0; j < T; j++) xvs[j] = (float)xp[j * D_INNER];
#pragma unroll
    for (int j = 0; j < T; j++) zvs[j] = (float)zp[j * 2 * D_INNER];

#pragma unroll
    for (int l = 0; l < T; ++l) {
        float dx = dvs[l] * xvs[l];
        float y  = Dv * xvs[l];
#pragma unroll
        for (int n = 0; n < 16; n++) {
            float dA = __expf(dvs[l] * Aa[n]);
            h[n] = dA * h[n] + dx * BCs[l][n];
            y   += h[n] * BCs[l][16 + n];
        }
        float zv = zvs[l];
        yp[l * D_INNER] = (bf16_t)(y * (zv / (1.f + __expf(-zv))));
    }
}

// ---------------------------------------------------------------------------
// out_proj: out[2048][512] += yz @ wop^T (K=1024), 64x64 tile.
// ---------------------------------------------------------------------------
__global__ __launch_bounds__(256) void outproj_gemm(const bf16_t* __restrict__ A,
                                                    const bf16_t* __restrict__ W,
                                                    float* __restrict__ out) {
    __shared__ bf16_t As[64][40];
    __shared__ bf16_t Bs[64][40];
    int tid = threadIdx.x;
    int m0 = blockIdx.y * 64, n0 = blockIdx.x * 64;
    int wid = tid >> 6, lane = tid & 63;
    int wm = (wid >> 1) * 32, wn = (wid & 1) * 32;
    int lr = lane & 15, kg = lane >> 4;

    f32x4 acc[2][2] = {};
    int srow = tid >> 2, scol = (tid & 3) * 8;
    const bf16_t* Ap = A + (size_t)(m0 + srow) * D_INNER + scol;
    const bf16_t* Wp = W + (size_t)(n0 + srow) * D_INNER + scol;

    for (int k0 = 0; k0 < D_INNER; k0 += 32) {
        *(bf16x8*)&As[srow][scol] = *(const bf16x8*)(Ap + k0);
        *(bf16x8*)&Bs[srow][scol] = *(const bf16x8*)(Wp + k0);
        __syncthreads();
        bf16x8 a0 = *(const bf16x8*)&As[wm + lr][kg * 8];
        bf16x8 a1 = *(const bf16x8*)&As[wm + 16 + lr][kg * 8];
        bf16x8 b0 = *(const bf16x8*)&Bs[wn + lr][kg * 8];
        bf16x8 b1 = *(const bf16x8*)&Bs[wn + 16 + lr][kg * 8];
        acc[0][0] = __builtin_amdgcn_mfma_f32_16x16x32_bf16(a0, b0, acc[0][0], 0, 0, 0);
        acc[0][1] = __builtin_amdgcn_mfma_f32_16x16x32_bf16(a0, b1, acc[0][1], 0, 0, 0);
        acc[1][0] = __builtin_amdgcn_mfma_f32_16x16x32_bf16(a1, b0, acc[1][0], 0, 0, 0);
        acc[1][1] = __builtin_amdgcn_mfma_f32_16x16x32_bf16(a1, b1, acc[1][1], 0, 0, 0);
        __syncthreads();
    }

    int colb = lane & 15, rowb = (lane >> 4) * 4;
#pragma unroll
    for (int fm = 0; fm < 2; fm++)
#pragma unroll
        for (int fn = 0; fn < 2; fn++)
#pragma unroll
            for (int r = 0; r < 4; r++) {
                int row = m0 + wm + fm * 16 + rowb + r;
                int col = n0 + wn + fn * 16 + colb;
                out[(size_t)row * D_MODEL + col] += acc[fm][fn][r];
            }
}

// ---------------------------------------------------------------------------
extern "C" void kernel_launch(void* const* d_in, const int* in_sizes, int n_in,
                              void* d_out, int out_size, void* d_ws, size_t ws_size,
                              hipStream_t stream) {
    const float* x_in  = (const float*)d_in[0];
    const float* ipw   = (const float*)d_in[1];
    const float* cw    = (const float*)d_in[2];
    const float* cb    = (const float*)d_in[3];
    const float* xpw   = (const float*)d_in[4];
    const float* dtw   = (const float*)d_in[5];
    const float* dtb   = (const float*)d_in[6];
    const float* A_log = (const float*)d_in[7];
    const float* Dsk   = (const float*)d_in[8];
    const float* opw   = (const float*)d_in[9];
    const float* nw    = (const float*)d_in[10];
    float* out = (float*)d_out;

    char* ws = (char*)d_ws;
    size_t off = 0;
    auto alloc = [&](size_t bytes) -> void* {
        void* p = ws + off;
        off += (bytes + 255) & ~(size_t)255;
        return p;
    };
    bf16_t* wip    = (bf16_t*)alloc((size_t)CVT_N1 * 2);
    bf16_t* wxp    = (bf16_t*)alloc((size_t)CVT_N2 * 2);
    bf16_t* wdt    = (bf16_t*)alloc((size_t)CVT_N3 * 2);
    bf16_t* wop    = (bf16_t*)alloc((size_t)CVT_N4 * 2);
    bf16_t* xz_bf  = (bf16_t*)alloc((size_t)NTOK * 2 * D_INNER * 2);
    bf16_t* xc_bf  = (bf16_t*)alloc((size_t)NTOK * D_INNER * 2);
    float*  dbcf   = (float*)alloc((size_t)NTOK * 64 * 4);
    float*  deltaf = (float*)alloc((size_t)NTOK * D_INNER * 4);
    bf16_t* yz_bf  = (bf16_t*)alloc((size_t)NTOK * D_INNER * 2);
    float*  scales = (float*)alloc((size_t)NTOK * 4);

    int nc = 64;
    if (off + (size_t)B_SZ * nc * 32 * D_INNER * 4 > ws_size) nc = 32;
    float* cstate = (float*)alloc((size_t)B_SZ * nc * 32 * D_INNER * 4);

    cvt_all<<<CVT_BLOCKS, 256, 0, stream>>>(ipw, xpw, dtw, opw, x_in,
                                            wip, wxp, wdt, wop, out);

    for (int l = 0; l < N_LAYERS; ++l) {
        const float* Al = A_log + (size_t)l * D_INNER * D_STATE;
        rms_scale<<<NTOK / 4, 256, 0, stream>>>(out, scales, dbcf);
        inproj_gemm<<<dim3(2 * D_INNER / 128, NTOK / 128), 256, 0, stream>>>(
            out, scales, nw + (size_t)l * D_MODEL,
            wip + (size_t)l * 2 * D_INNER * D_MODEL, xz_bf);
        xproj_conv<<<dim3(8, NTOK / 64), 256, 0, stream>>>(
            xz_bf, cw + (size_t)l * D_INNER * D_CONV, cb + (size_t)l * D_INNER,
            wxp + (size_t)l * 64 * D_INNER, xc_bf, dbcf);
        dtproj<<<dim3(D_INNER / 64, NTOK / 64), 256, 0, stream>>>(
            dbcf, wdt + (size_t)l * D_INNER * DT_RANK,
            dtb + (size_t)l * D_INNER, deltaf);
        if (nc == 64) {
            scan_part1<16><<<dim3(D_INNER / 256, nc, B_SZ), 256, 0, stream>>>(
                deltaf, xc_bf, dbcf, Al, cstate, nc);
        } else {
            scan_part1<32><<<dim3(D_INNER / 256, nc, B_SZ), 256, 0, stream>>>(
                deltaf, xc_bf, dbcf, Al, cstate, nc);
        }
        scan_combine<<<dim3(D_INNER / 256, D_STATE, B_SZ), 256, 0, stream>>>(
            cstate, nc);
        if (nc == 64) {
            scan_part3<16><<<dim3(D_INNER / 256, nc, B_SZ), 256, 0, stream>>>(
                deltaf, xc_bf, dbcf, xz_bf, Al, Dsk + (size_t)l * D_INNER, cstate,
                yz_bf, nc);
        } else {
            scan_part3<32><<<dim3(D_INNER / 256, nc, B_SZ), 256, 0, stream>>>(
                deltaf, xc_bf, dbcf, xz_bf, Al, Dsk + (size_t)l * D_INNER, cstate,
                yz_bf, nc);
        }
        outproj_gemm<<<dim3(D_MODEL / 64, NTOK / 64), 256, 0, stream>>>(
            yz_bf, wop + (size_t)l * D_MODEL * D_INNER, out);
    }
}

// Round 5
// 278.443 us; speedup vs baseline: 2.2106x; 1.0525x over previous
//
#include <hip/hip_runtime.h>
#include <hip/hip_bf16.h>
#include <math.h>

#define D_MODEL   512
#define N_LAYERS  3
#define D_INNER   1024
#define DT_RANK   32
#define D_STATE   16
#define D_CONV    4
#define RMS_EPS   1e-5f
#define B_SZ      2
#define L_SEQ     1024
#define NTOK      (B_SZ * L_SEQ)   // 2048
#define NC        64               // chunks per sequence
#define CT        16               // tokens per chunk

typedef __bf16 bf16_t;
typedef bf16_t bf16x8 __attribute__((ext_vector_type(8)));
typedef float  f32x4  __attribute__((ext_vector_type(4)));

// ---------------------------------------------------------------------------
// One-shot: convert all 4 weight tensors f32->bf16 (8 elems/thread) and copy
// the residual x -> out (4 f32/thread). Segmented flat index.
// ---------------------------------------------------------------------------
#define CVT_N1 (N_LAYERS * 2 * D_INNER * D_MODEL)
#define CVT_N2 (N_LAYERS * 64 * D_INNER)
#define CVT_N3 (N_LAYERS * D_INNER * DT_RANK)
#define CVT_N4 (N_LAYERS * D_MODEL * D_INNER)
#define CVT_S1 (CVT_N1 / 8)
#define CVT_S2 (CVT_S1 + CVT_N2 / 8)
#define CVT_S3 (CVT_S2 + CVT_N3 / 8)
#define CVT_S4 (CVT_S3 + CVT_N4 / 8)
#define CVT_S5 (CVT_S4 + NTOK * D_MODEL / 4)
#define CVT_BLOCKS ((CVT_S5 + 255) / 256)

__device__ __forceinline__ void cvt8(const float* s, bf16_t* d, int idx) {
    int i = idx * 8;
    f32x4 v0 = *(const f32x4*)&s[i];
    f32x4 v1 = *(const f32x4*)&s[i + 4];
    bf16x8 o;
#pragma unroll
    for (int j = 0; j < 4; j++) { o[j] = (bf16_t)v0[j]; o[j + 4] = (bf16_t)v1[j]; }
    *(bf16x8*)&d[i] = o;
}

__global__ __launch_bounds__(256) void cvt_all(const float* __restrict__ ipw,
                                               const float* __restrict__ xpw,
                                               const float* __restrict__ dtw,
                                               const float* __restrict__ opw,
                                               const float* __restrict__ x,
                                               bf16_t* __restrict__ wip,
                                               bf16_t* __restrict__ wxp,
                                               bf16_t* __restrict__ wdt,
                                               bf16_t* __restrict__ wop,
                                               float* __restrict__ out) {
    int t = blockIdx.x * 256 + threadIdx.x;
    if (t < CVT_S1)      cvt8(ipw, wip, t);
    else if (t < CVT_S2) cvt8(xpw, wxp, t - CVT_S1);
    else if (t < CVT_S3) cvt8(dtw, wdt, t - CVT_S2);
    else if (t < CVT_S4) cvt8(opw, wop, t - CVT_S3);
    else if (t < CVT_S5) {
        int i = (t - CVT_S4) * 4;
        *(f32x4*)&out[i] = *(const f32x4*)&x[i];
    }
}

// ---------------------------------------------------------------------------
// Per-token RMS scale + zero the dbc accumulator (2048*64 = grid*block exact).
// ---------------------------------------------------------------------------
__global__ __launch_bounds__(256) void rms_scale(const float* __restrict__ x,
                                                 float* __restrict__ scales,
                                                 float* __restrict__ dbcf) {
    dbcf[blockIdx.x * 256 + threadIdx.x] = 0.f;
    int wid  = threadIdx.x >> 6;
    int lane = threadIdx.x & 63;
    int token = blockIdx.x * 4 + wid;
    const float* xr = x + (size_t)token * D_MODEL;
    f32x4 v0 = *(const f32x4*)&xr[lane * 8];
    f32x4 v1 = *(const f32x4*)&xr[lane * 8 + 4];
    float ss = 0.f;
#pragma unroll
    for (int i = 0; i < 4; i++) ss += v0[i] * v0[i] + v1[i] * v1[i];
#pragma unroll
    for (int m = 32; m >= 1; m >>= 1) ss += __shfl_xor(ss, m, 64);
    if (lane == 0) scales[token] = rsqrtf(ss * (1.0f / D_MODEL) + RMS_EPS);
}

// ---------------------------------------------------------------------------
// in_proj: xz[2048][2048] = (x * scale * nw) @ wip^T, 128x128 tile, BK=64.
// RMSNorm fused into A-staging. 2 MFMA sub-steps per barrier pair.
// ---------------------------------------------------------------------------
__global__ __launch_bounds__(256) void inproj_gemm(const float* __restrict__ x,
                                                   const float* __restrict__ scales,
                                                   const float* __restrict__ nw,
                                                   const bf16_t* __restrict__ W,
                                                   bf16_t* __restrict__ xz) {
    __shared__ bf16_t As[128][72];   // 64 + 8 pad
    __shared__ bf16_t Bs[128][72];
    int tid = threadIdx.x;
    int m0 = blockIdx.y * 128, n0 = blockIdx.x * 128;
    int wid = tid >> 6, lane = tid & 63;
    int wm = (wid >> 1) * 64, wn = (wid & 1) * 64;
    int lr = lane & 15, kg = lane >> 4;

    f32x4 acc[4][4] = {};

    int srow = tid >> 1, scol = (tid & 1) * 32;
    float rs = scales[m0 + srow];
    const float*  xp = x + (size_t)(m0 + srow) * D_MODEL + scol;
    const bf16_t* wp = W + (size_t)(n0 + srow) * D_MODEL + scol;

    for (int k0 = 0; k0 < D_MODEL; k0 += 64) {
#pragma unroll
        for (int g = 0; g < 4; g++) {
            f32x4 v0 = *(const f32x4*)(xp + k0 + g * 8);
            f32x4 v1 = *(const f32x4*)(xp + k0 + g * 8 + 4);
            f32x4 g0 = *(const f32x4*)(nw + k0 + scol + g * 8);
            f32x4 g1 = *(const f32x4*)(nw + k0 + scol + g * 8 + 4);
            bf16x8 a;
#pragma unroll
            for (int j = 0; j < 4; j++) {
                a[j]     = (bf16_t)(v0[j] * rs * g0[j]);
                a[j + 4] = (bf16_t)(v1[j] * rs * g1[j]);
            }
            *(bf16x8*)&As[srow][scol + g * 8] = a;
            *(bf16x8*)&Bs[srow][scol + g * 8] = *(const bf16x8*)(wp + k0 + g * 8);
        }
        __syncthreads();
#pragma unroll
        for (int kk = 0; kk < 2; kk++) {
            bf16x8 af[4], bfr[4];
#pragma unroll
            for (int f = 0; f < 4; f++) {
                af[f]  = *(const bf16x8*)&As[wm + f * 16 + lr][kk * 32 + kg * 8];
                bfr[f] = *(const bf16x8*)&Bs[wn + f * 16 + lr][kk * 32 + kg * 8];
            }
#pragma unroll
            for (int fm = 0; fm < 4; fm++)
#pragma unroll
                for (int fn = 0; fn < 4; fn++)
                    acc[fm][fn] = __builtin_amdgcn_mfma_f32_16x16x32_bf16(af[fm], bfr[fn], acc[fm][fn], 0, 0, 0);
        }
        __syncthreads();
    }

    int colb = lane & 15, rowb = (lane >> 4) * 4;
#pragma unroll
    for (int fm = 0; fm < 4; fm++)
#pragma unroll
        for (int fn = 0; fn < 4; fn++)
#pragma unroll
            for (int r = 0; r < 4; r++) {
                int row = m0 + wm + fm * 16 + rowb + r;
                int col = n0 + wn + fn * 16 + colb;
                xz[(size_t)row * (2 * D_INNER) + col] = (bf16_t)acc[fm][fn][r];
            }
}

// ---------------------------------------------------------------------------
// x_proj with fused depthwise conv+silu, split-K (8 kc x 32 token-tiles).
// A-staging computes xc = silu(conv(xz)+cb), stores xc, MFMA, atomicAdd dbcf.
// ---------------------------------------------------------------------------
__global__ __launch_bounds__(256) void xproj_conv(const bf16_t* __restrict__ xz,
                                                  const float* __restrict__ cw,
                                                  const float* __restrict__ cb,
                                                  const bf16_t* __restrict__ Wx,
                                                  bf16_t* __restrict__ xc,
                                                  float* __restrict__ dbcf) {
    __shared__ bf16_t As[64][40];
    __shared__ bf16_t Bs[64][40];
    int tid = threadIdx.x;
    int kc = blockIdx.x;
    int m0 = blockIdx.y * 64;
    int wid = tid >> 6, lane = tid & 63;
    int wm = (wid >> 1) * 32, wn = (wid & 1) * 32;
    int lr = lane & 15, kg = lane >> 4;

    f32x4 acc[2][2] = {};
    int srow = tid >> 2, scol = (tid & 3) * 8;
    int token = m0 + srow;
    int l = token & (L_SEQ - 1);
    const bf16_t* base = xz + (size_t)token * (2 * D_INNER) + kc * 128 + scol;
    const bf16_t* b1 = base - (l >= 1 ? 1 : 0) * 2 * D_INNER;
    const bf16_t* b2 = base - (l >= 2 ? 2 : 0) * 2 * D_INNER;
    const bf16_t* b3 = base - (l >= 3 ? 3 : 0) * 2 * D_INNER;
    const bf16_t* wrow = Wx + (size_t)srow * D_INNER + kc * 128 + scol;

    for (int k0 = 0; k0 < 128; k0 += 32) {
        int e = kc * 128 + k0 + scol;
        bf16x8 t0v = *(const bf16x8*)(base + k0);
        bf16x8 t1v = *(const bf16x8*)(b1 + k0);
        bf16x8 t2v = *(const bf16x8*)(b2 + k0);
        bf16x8 t3v = *(const bf16x8*)(b3 + k0);
        bf16x8 a;
#pragma unroll
        for (int j = 0; j < 8; j++) {
            f32x4 w = *(const f32x4*)&cw[(e + j) * 4];
            float av = cb[e + j] + w[3] * (float)t0v[j];
            if (l >= 1) av += w[2] * (float)t1v[j];
            if (l >= 2) av += w[1] * (float)t2v[j];
            if (l >= 3) av += w[0] * (float)t3v[j];
            a[j] = (bf16_t)(av / (1.f + __expf(-av)));
        }
        *(bf16x8*)&As[srow][scol] = a;
        *(bf16x8*)&xc[(size_t)token * D_INNER + e] = a;
        *(bf16x8*)&Bs[srow][scol] = *(const bf16x8*)(wrow + k0);
        __syncthreads();
        bf16x8 a0 = *(const bf16x8*)&As[wm + lr][kg * 8];
        bf16x8 a1 = *(const bf16x8*)&As[wm + 16 + lr][kg * 8];
        bf16x8 b0 = *(const bf16x8*)&Bs[wn + lr][kg * 8];
        bf16x8 bb1 = *(const bf16x8*)&Bs[wn + 16 + lr][kg * 8];
        acc[0][0] = __builtin_amdgcn_mfma_f32_16x16x32_bf16(a0, b0, acc[0][0], 0, 0, 0);
        acc[0][1] = __builtin_amdgcn_mfma_f32_16x16x32_bf16(a0, bb1, acc[0][1], 0, 0, 0);
        acc[1][0] = __builtin_amdgcn_mfma_f32_16x16x32_bf16(a1, b0, acc[1][0], 0, 0, 0);
        acc[1][1] = __builtin_amdgcn_mfma_f32_16x16x32_bf16(a1, bb1, acc[1][1], 0, 0, 0);
        __syncthreads();
    }

    int colb = lane & 15, rowb = (lane >> 4) * 4;
#pragma unroll
    for (int fm = 0; fm < 2; fm++)
#pragma unroll
        for (int fn = 0; fn < 2; fn++)
#pragma unroll
            for (int r = 0; r < 4; r++) {
                int row = m0 + wm + fm * 16 + rowb + r;
                int col = wn + fn * 16 + colb;
                atomicAdd(&dbcf[(size_t)row * 64 + col], acc[fm][fn][r]);
            }
}

// ---------------------------------------------------------------------------
// dt_proj + softplus + chunk-local scan (pass 1), fused.
// Grid (16 e-tiles, 32 token-tiles). GEMM phase: delta(64x64) =
// softplus(dbcf[:, :32] @ Wd^T + dtb) -> global delta + LDS. Scan phase:
// 256 threads = 4 chunks x 64 e, each scans CT=16 tokens with 16 states in
// registers; stores P[16], hf[16] to cs.
// ---------------------------------------------------------------------------
__global__ __launch_bounds__(256) void dtscan1(const float* __restrict__ dbcf,
                                               const bf16_t* __restrict__ Wd,
                                               const float* __restrict__ dtb,
                                               const bf16_t* __restrict__ xc,
                                               const float* __restrict__ A_log,
                                               float* __restrict__ delta,
                                               float* __restrict__ cs) {
    __shared__ bf16_t As[64][40];
    __shared__ bf16_t Bw[64][40];
    __shared__ float  ds_[64][65];   // delta tile (f32, padded)
    __shared__ float  Bsc[64][17];   // B rows for these 64 tokens
    int tid = threadIdx.x;
    int n0 = blockIdx.x * 64, m0 = blockIdx.y * 64;
    int wid = tid >> 6, lane = tid & 63;
    int wm = (wid >> 1) * 32, wn = (wid & 1) * 32;
    int lr = lane & 15, kg = lane >> 4;

    // --- GEMM phase (single K=32 step) ---
    int srow = tid >> 2, scol = (tid & 3) * 8;
    f32x4 v0 = *(const f32x4*)&dbcf[(size_t)(m0 + srow) * 64 + scol];
    f32x4 v1 = *(const f32x4*)&dbcf[(size_t)(m0 + srow) * 64 + scol + 4];
    bf16x8 a;
#pragma unroll
    for (int j = 0; j < 4; j++) { a[j] = (bf16_t)v0[j]; a[j + 4] = (bf16_t)v1[j]; }
    *(bf16x8*)&As[srow][scol] = a;
    *(bf16x8*)&Bw[srow][scol] = *(const bf16x8*)(Wd + (size_t)(n0 + srow) * DT_RANK + scol);
    __syncthreads();

    bf16x8 a0 = *(const bf16x8*)&As[wm + lr][kg * 8];
    bf16x8 a1 = *(const bf16x8*)&As[wm + 16 + lr][kg * 8];
    bf16x8 b0 = *(const bf16x8*)&Bw[wn + lr][kg * 8];
    bf16x8 b1 = *(const bf16x8*)&Bw[wn + 16 + lr][kg * 8];
    f32x4 acc[2][2] = {};
    acc[0][0] = __builtin_amdgcn_mfma_f32_16x16x32_bf16(a0, b0, acc[0][0], 0, 0, 0);
    acc[0][1] = __builtin_amdgcn_mfma_f32_16x16x32_bf16(a0, b1, acc[0][1], 0, 0, 0);
    acc[1][0] = __builtin_amdgcn_mfma_f32_16x16x32_bf16(a1, b0, acc[1][0], 0, 0, 0);
    acc[1][1] = __builtin_amdgcn_mfma_f32_16x16x32_bf16(a1, b1, acc[1][1], 0, 0, 0);

    int colb = lane & 15, rowb = (lane >> 4) * 4;
#pragma unroll
    for (int fm = 0; fm < 2; fm++)
#pragma unroll
        for (int fn = 0; fn < 2; fn++)
#pragma unroll
            for (int r = 0; r < 4; r++) {
                int row = wm + fm * 16 + rowb + r;       // local token
                int el  = wn + fn * 16 + colb;           // local e
                float t = acc[fm][fn][r] + dtb[n0 + el];
                float sp = (t > 15.f) ? t : log1pf(__expf(t));
                delta[(size_t)(m0 + row) * D_INNER + (n0 + el)] = sp;
                ds_[row][el] = sp;
            }
    for (int i = tid; i < 64 * 16; i += 256)
        Bsc[i >> 4][i & 15] = dbcf[(size_t)(m0 + (i >> 4)) * 64 + 32 + (i & 15)];
    __syncthreads();

    // --- scan phase: 4 chunks x 64 e ---
    int cl = tid >> 6, el = tid & 63;
    int e  = n0 + el;
    int b  = m0 >> 10;                                   // token/L_SEQ
    int chunk = ((m0 & (L_SEQ - 1)) >> 4) + cl;

    float Aa[16], h[16], P[16];
    const float* Ae = A_log + (size_t)e * D_STATE;
#pragma unroll
    for (int n = 0; n < 16; n++) { Aa[n] = -__expf(Ae[n]); h[n] = 0.f; P[n] = 1.f; }

    const bf16_t* xp = xc + (size_t)(m0 + cl * CT) * D_INNER + e;
    float xvs[CT];
#pragma unroll
    for (int j = 0; j < CT; j++) xvs[j] = (float)xp[j * D_INNER];

#pragma unroll
    for (int l = 0; l < CT; ++l) {
        float dv = ds_[cl * CT + l][el];
        float dx = dv * xvs[l];
#pragma unroll
        for (int n = 0; n < 16; n++) {
            float dA = __expf(dv * Aa[n]);
            h[n] = dA * h[n] + dx * Bsc[cl * CT + l][n];
            P[n] *= dA;
        }
    }

    float* o = cs + (size_t)(b * NC + chunk) * 32 * D_INNER + e;
#pragma unroll
    for (int n = 0; n < 16; n++) {
        o[n * D_INNER]        = P[n];
        o[(16 + n) * D_INNER] = h[n];
    }
}

// ---------------------------------------------------------------------------
// Pass 2: sequential combine over chunks; batch-8 prefetch to hide latency.
// ---------------------------------------------------------------------------
__global__ __launch_bounds__(256) void scan_combine(float* __restrict__ cs) {
    int e = blockIdx.x * 256 + threadIdx.x;
    int n = blockIdx.y;
    int b = blockIdx.z;
    size_t stride = (size_t)32 * D_INNER;
    float* p = cs + ((size_t)b * NC * 32 + n) * D_INNER + e;

    float h = 0.f;
    for (int base = 0; base < NC; base += 8) {
        float Pv[8], hv[8];
#pragma unroll
        for (int j = 0; j < 8; j++) {
            Pv[j] = p[(base + j) * stride];
            hv[j] = p[(base + j) * stride + 16 * D_INNER];
        }
#pragma unroll
        for (int j = 0; j < 8; j++) {
            p[(base + j) * stride] = h;
            h = Pv[j] * h + hv[j];
        }
    }
}

// ---------------------------------------------------------------------------
// Pass 3: re-scan seeded with h_init; fuse y = (sum h*C + D*x)*silu(z) -> bf16.
// ---------------------------------------------------------------------------
__global__ __launch_bounds__(256) void scan_part3(const float* __restrict__ delta,
                                                  const bf16_t* __restrict__ xc,
                                                  const float* __restrict__ dbcf,
                                                  const bf16_t* __restrict__ xz,
                                                  const float* __restrict__ A_log,
                                                  const float* __restrict__ Dskip,
                                                  const float* __restrict__ cs,
                                                  bf16_t* __restrict__ yz) {
    int e = blockIdx.x * 256 + threadIdx.x;
    int c = blockIdx.y;
    int b = blockIdx.z;
    size_t t0 = (size_t)b * L_SEQ + (size_t)c * CT;

    __shared__ float BCs[CT][32];
    for (int i = threadIdx.x; i < CT * 32; i += 256)
        BCs[i >> 5][i & 31] = dbcf[(t0 + (i >> 5)) * 64 + 32 + (i & 31)];
    __syncthreads();

    float Aa[16], h[16];
    const float* Ae = A_log + (size_t)e * D_STATE;
    const float* hi = cs + (size_t)(b * NC + c) * 32 * D_INNER + e;
#pragma unroll
    for (int n = 0; n < 16; n++) {
        Aa[n] = -__expf(Ae[n]);
        h[n]  = hi[n * D_INNER];
    }
    float Dv = Dskip[e];

    const float*  dp = delta + t0 * D_INNER + e;
    const bf16_t* xp = xc    + t0 * D_INNER + e;
    const bf16_t* zp = xz    + t0 * 2 * D_INNER + D_INNER + e;
    bf16_t*       yp = yz    + t0 * D_INNER + e;

    float dvs[CT], xvs[CT], zvs[CT];
#pragma unroll
    for (int j = 0; j < CT; j++) dvs[j] = dp[j * D_INNER];
#pragma unroll
    for (int j = 0; j < CT; j++) xvs[j] = (float)xp[j * D_INNER];
#pragma unroll
    for (int j = 0; j < CT; j++) zvs[j] = (float)zp[j * 2 * D_INNER];

#pragma unroll
    for (int l = 0; l < CT; ++l) {
        float dx = dvs[l] * xvs[l];
        float y  = Dv * xvs[l];
#pragma unroll
        for (int n = 0; n < 16; n++) {
            float dA = __expf(dvs[l] * Aa[n]);
            h[n] = dA * h[n] + dx * BCs[l][n];
            y   += h[n] * BCs[l][16 + n];
        }
        float zv = zvs[l];
        yp[l * D_INNER] = (bf16_t)(y * (zv / (1.f + __expf(-zv))));
    }
}

// ---------------------------------------------------------------------------
// out_proj: out[2048][512] += yz @ wop^T (K=1024), 64x64 tile, BK=64.
// ---------------------------------------------------------------------------
__global__ __launch_bounds__(256) void outproj_gemm(const bf16_t* __restrict__ A,
                                                    const bf16_t* __restrict__ W,
                                                    float* __restrict__ out) {
    __shared__ bf16_t As[64][72];
    __shared__ bf16_t Bs[64][72];
    int tid = threadIdx.x;
    int m0 = blockIdx.y * 64, n0 = blockIdx.x * 64;
    int wid = tid >> 6, lane = tid & 63;
    int wm = (wid >> 1) * 32, wn = (wid & 1) * 32;
    int lr = lane & 15, kg = lane >> 4;

    f32x4 acc[2][2] = {};
    int srow = tid >> 2, scol = (tid & 3) * 16;
    const bf16_t* Ap = A + (size_t)(m0 + srow) * D_INNER + scol;
    const bf16_t* Wp = W + (size_t)(n0 + srow) * D_INNER + scol;

    for (int k0 = 0; k0 < D_INNER; k0 += 64) {
        *(bf16x8*)&As[srow][scol]     = *(const bf16x8*)(Ap + k0);
        *(bf16x8*)&As[srow][scol + 8] = *(const bf16x8*)(Ap + k0 + 8);
        *(bf16x8*)&Bs[srow][scol]     = *(const bf16x8*)(Wp + k0);
        *(bf16x8*)&Bs[srow][scol + 8] = *(const bf16x8*)(Wp + k0 + 8);
        __syncthreads();
#pragma unroll
        for (int kk = 0; kk < 2; kk++) {
            bf16x8 a0 = *(const bf16x8*)&As[wm + lr][kk * 32 + kg * 8];
            bf16x8 a1 = *(const bf16x8*)&As[wm + 16 + lr][kk * 32 + kg * 8];
            bf16x8 b0 = *(const bf16x8*)&Bs[wn + lr][kk * 32 + kg * 8];
            bf16x8 b1 = *(const bf16x8*)&Bs[wn + 16 + lr][kk * 32 + kg * 8];
            acc[0][0] = __builtin_amdgcn_mfma_f32_16x16x32_bf16(a0, b0, acc[0][0], 0, 0, 0);
            acc[0][1] = __builtin_amdgcn_mfma_f32_16x16x32_bf16(a0, b1, acc[0][1], 0, 0, 0);
            acc[1][0] = __builtin_amdgcn_mfma_f32_16x16x32_bf16(a1, b0, acc[1][0], 0, 0, 0);
            acc[1][1] = __builtin_amdgcn_mfma_f32_16x16x32_bf16(a1, b1, acc[1][1], 0, 0, 0);
        }
        __syncthreads();
    }

    int colb = lane & 15, rowb = (lane >> 4) * 4;
#pragma unroll
    for (int fm = 0; fm < 2; fm++)
#pragma unroll
        for (int fn = 0; fn < 2; fn++)
#pragma unroll
            for (int r = 0; r < 4; r++) {
                int row = m0 + wm + fm * 16 + rowb + r;
                int col = n0 + wn + fn * 16 + colb;
                out[(size_t)row * D_MODEL + col] += acc[fm][fn][r];
            }
}

// ---------------------------------------------------------------------------
extern "C" void kernel_launch(void* const* d_in, const int* in_sizes, int n_in,
                              void* d_out, int out_size, void* d_ws, size_t ws_size,
                              hipStream_t stream) {
    const float* x_in  = (const float*)d_in[0];
    const float* ipw   = (const float*)d_in[1];
    const float* cw    = (const float*)d_in[2];
    const float* cb    = (const float*)d_in[3];
    const float* xpw   = (const float*)d_in[4];
    const float* dtw   = (const float*)d_in[5];
    const float* dtb   = (const float*)d_in[6];
    const float* A_log = (const float*)d_in[7];
    const float* Dsk   = (const float*)d_in[8];
    const float* opw   = (const float*)d_in[9];
    const float* nw    = (const float*)d_in[10];
    float* out = (float*)d_out;

    char* ws = (char*)d_ws;
    size_t off = 0;
    auto alloc = [&](size_t bytes) -> void* {
        void* p = ws + off;
        off += (bytes + 255) & ~(size_t)255;
        return p;
    };
    bf16_t* wip    = (bf16_t*)alloc((size_t)CVT_N1 * 2);
    bf16_t* wxp    = (bf16_t*)alloc((size_t)CVT_N2 * 2);
    bf16_t* wdt    = (bf16_t*)alloc((size_t)CVT_N3 * 2);
    bf16_t* wop    = (bf16_t*)alloc((size_t)CVT_N4 * 2);
    bf16_t* xz_bf  = (bf16_t*)alloc((size_t)NTOK * 2 * D_INNER * 2);
    bf16_t* xc_bf  = (bf16_t*)alloc((size_t)NTOK * D_INNER * 2);
    float*  dbcf   = (float*)alloc((size_t)NTOK * 64 * 4);
    float*  deltaf = (float*)alloc((size_t)NTOK * D_INNER * 4);
    bf16_t* yz_bf  = (bf16_t*)alloc((size_t)NTOK * D_INNER * 2);
    float*  scales = (float*)alloc((size_t)NTOK * 4);
    float*  cstate = (float*)alloc((size_t)B_SZ * NC * 32 * D_INNER * 4);

    cvt_all<<<CVT_BLOCKS, 256, 0, stream>>>(ipw, xpw, dtw, opw, x_in,
                                            wip, wxp, wdt, wop, out);

    for (int l = 0; l < N_LAYERS; ++l) {
        const float* Al = A_log + (size_t)l * D_INNER * D_STATE;
        rms_scale<<<NTOK / 4, 256, 0, stream>>>(out, scales, dbcf);
        inproj_gemm<<<dim3(2 * D_INNER / 128, NTOK / 128), 256, 0, stream>>>(
            out, scales, nw + (size_t)l * D_MODEL,
            wip + (size_t)l * 2 * D_INNER * D_MODEL, xz_bf);
        xproj_conv<<<dim3(8, NTOK / 64), 256, 0, stream>>>(
            xz_bf, cw + (size_t)l * D_INNER * D_CONV, cb + (size_t)l * D_INNER,
            wxp + (size_t)l * 64 * D_INNER, xc_bf, dbcf);
        dtscan1<<<dim3(D_INNER / 64, NTOK / 64), 256, 0, stream>>>(
            dbcf, wdt + (size_t)l * D_INNER * DT_RANK, dtb + (size_t)l * D_INNER,
            xc_bf, Al, deltaf, cstate);
        scan_combine<<<dim3(D_INNER / 256, D_STATE, B_SZ), 256, 0, stream>>>(cstate);
        scan_part3<<<dim3(D_INNER / 256, NC, B_SZ), 256, 0, stream>>>(
            deltaf, xc_bf, dbcf, xz_bf, Al, Dsk + (size_t)l * D_INNER, cstate, yz_bf);
        outproj_gemm<<<dim3(D_MODEL / 64, NTOK / 64), 256, 0, stream>>>(
            yz_bf, wop + (size_t)l * D_MODEL * D_INNER, out);
    }
}